// Round 3
// baseline (316.619 us; speedup 1.0000x reference)
//
#include <hip/hip_runtime.h>
#include <hip/hip_bf16.h>

typedef __hip_bfloat16 bf16;

// Broadcast lane l's float value to all lanes (l compile-time/uniform, full exec).
static __device__ __forceinline__ float lane_bcast_f(float v, int l) {
    return __uint_as_float(__builtin_amdgcn_readlane(__float_as_uint(v), l));
}

// Load 4 consecutive values as float4 (fp32 direct, bf16 converted).
static __device__ __forceinline__ float4 load4f(const float* p) {
    return *(const float4*)p;
}
static __device__ __forceinline__ float4 load4f(const bf16* p) {
    const ushort4 s = *(const ushort4*)p;
    float4 r;
    r.x = __uint_as_float((unsigned)s.x << 16);
    r.y = __uint_as_float((unsigned)s.y << 16);
    r.z = __uint_as_float((unsigned)s.z << 16);
    r.w = __uint_as_float((unsigned)s.w << 16);
    return r;
}

// Hop-1 layer: agg = mean_k feats[nid2[idx1[row][k]]], h1 = relu(agg@W0 + b0).
// Gather layout: lane = (sub<<4)|c4. Quarter-wave `sub` covers neighbor ks
// {sub, 4+sub, ..., 28+sub}; lane loads float4 of columns 4*c4..4*c4+3.
// Each wave processes 2 rows per iteration (16 independent 1KB loads in flight).
template <typename HT>
__global__ __launch_bounds__(256) void k_hop1(
    const float* __restrict__ feats,  // [V,64] fp32
    const float* __restrict__ W0,     // [64,64]
    const float* __restrict__ b0,     // [64]
    const int*   __restrict__ idx1,   // [N1,32]
    const int*   __restrict__ nid2,   // [N2]
    HT*          __restrict__ h1,     // [N1,64] out
    int N1)
{
    const int lane = threadIdx.x & 63;
    const int sub  = lane >> 4;       // 0..3: which k-subset this lane gathers
    const int c4   = lane & 15;       // column group: cols 4*c4 .. 4*c4+3
    const int gwave = blockIdx.x * (blockDim.x >> 6) + (threadIdx.x >> 6);
    const int nwave = gridDim.x * (blockDim.x >> 6);

    // Per-lane column of W0 for the broadcast matmul: w0c[d] = W0[d][lane]
    float w0c[64];
#pragma unroll
    for (int d = 0; d < 64; ++d) w0c[d] = W0[d * 64 + lane];
    const float bias = b0[lane];

    const float4* f4 = (const float4*)feats;

    for (int base = 2 * gwave; base < N1; base += 2 * nwave) {
        const int r0 = base;
        const bool has_r1 = (base + 1 < N1);
        const int r1 = has_r1 ? base + 1 : base;

        // Each lane loads its own 8 neighbor positions (4 distinct addrs/wave
        // per i — broadcast-coalesced), then resolves node ids. All 16 nid2
        // loads are independent -> fully overlapped latency.
        int nk0[8], nk1[8];
#pragma unroll
        for (int i = 0; i < 8; ++i) {
            nk0[i] = idx1[r0 * 32 + 4 * i + sub];
            nk1[i] = idx1[r1 * 32 + 4 * i + sub];
        }
#pragma unroll
        for (int i = 0; i < 8; ++i) {
            nk0[i] = nid2[nk0[i]];
            nk1[i] = nid2[nk1[i]];
        }

        // 16 independent float4 gathers in flight.
        float a0[4] = {0.f, 0.f, 0.f, 0.f};
        float a1[4] = {0.f, 0.f, 0.f, 0.f};
#pragma unroll
        for (int i = 0; i < 8; ++i) {
            const float4 v0 = f4[(size_t)nk0[i] * 16 + c4];
            const float4 v1 = f4[(size_t)nk1[i] * 16 + c4];
            a0[0] += v0.x; a0[1] += v0.y; a0[2] += v0.z; a0[3] += v0.w;
            a1[0] += v1.x; a1[1] += v1.y; a1[2] += v1.z; a1[3] += v1.w;
        }

        // Combine the 4 quarter-wave partial sums (lanes c4, c4+16, c4+32, c4+48).
#pragma unroll
        for (int c = 0; c < 4; ++c) {
            a0[c] += __shfl_xor(a0[c], 16, 64);
            a0[c] += __shfl_xor(a0[c], 32, 64);
            a1[c] += __shfl_xor(a1[c], 16, 64);
            a1[c] += __shfl_xor(a1[c], 32, 64);
            a0[c] *= 0.03125f;
            a1[c] *= 0.03125f;
        }

        // Broadcast matmul: h[lane] = relu(b[lane] + sum_d agg[d]*W0[d][lane]).
        // agg[d] lives in lane (d>>2), component (d&3) — both fold at compile time.
        float h0 = bias, h1v = bias;
#pragma unroll
        for (int d = 0; d < 64; ++d) {
            h0  = fmaf(lane_bcast_f(a0[d & 3], d >> 2), w0c[d], h0);
            h1v = fmaf(lane_bcast_f(a1[d & 3], d >> 2), w0c[d], h1v);
        }
        h0  = fmaxf(h0, 0.f);
        h1v = fmaxf(h1v, 0.f);

        if constexpr (sizeof(HT) == 2) {
            h1[(size_t)r0 * 64 + lane] = __float2bfloat16(h0);
            if (has_r1) h1[(size_t)r1 * 64 + lane] = __float2bfloat16(h1v);
        } else {
            h1[(size_t)r0 * 64 + lane] = h0;
            if (has_r1) h1[(size_t)r1 * 64 + lane] = h1v;
        }
    }
}

// Seed layer: gather-mean over h1 rows (direct indices), W1+b1+relu, fp32 out.
template <typename HT>
__global__ __launch_bounds__(256) void k_hop0(
    const HT*    __restrict__ h1,     // [N1,64]
    const float* __restrict__ W1,     // [64,64]
    const float* __restrict__ b1,     // [64]
    const int*   __restrict__ idx0,   // [N0,32]
    float*       __restrict__ out,    // [N0,64] fp32
    int N0)
{
    const int lane = threadIdx.x & 63;
    const int sub  = lane >> 4;
    const int c4   = lane & 15;
    const int gwave = blockIdx.x * (blockDim.x >> 6) + (threadIdx.x >> 6);
    const int nwave = gridDim.x * (blockDim.x >> 6);

    float w1c[64];
#pragma unroll
    for (int d = 0; d < 64; ++d) w1c[d] = W1[d * 64 + lane];
    const float bias = b1[lane];

    for (int row = gwave; row < N0; row += nwave) {
        int jk[8];
#pragma unroll
        for (int i = 0; i < 8; ++i) jk[i] = idx0[row * 32 + 4 * i + sub];

        float a[4] = {0.f, 0.f, 0.f, 0.f};
#pragma unroll
        for (int i = 0; i < 8; ++i) {
            const float4 v = load4f(h1 + (size_t)jk[i] * 64 + c4 * 4);
            a[0] += v.x; a[1] += v.y; a[2] += v.z; a[3] += v.w;
        }
#pragma unroll
        for (int c = 0; c < 4; ++c) {
            a[c] += __shfl_xor(a[c], 16, 64);
            a[c] += __shfl_xor(a[c], 32, 64);
            a[c] *= 0.03125f;
        }

        float o = bias;
#pragma unroll
        for (int d = 0; d < 64; ++d)
            o = fmaf(lane_bcast_f(a[d & 3], d >> 2), w1c[d], o);
        out[(size_t)row * 64 + lane] = fmaxf(o, 0.f);
    }
}

extern "C" void kernel_launch(void* const* d_in, const int* in_sizes, int n_in,
                              void* d_out, int out_size, void* d_ws, size_t ws_size,
                              hipStream_t stream) {
    const float* feats = (const float*)d_in[0];
    const float* W0    = (const float*)d_in[1];
    const float* b0    = (const float*)d_in[2];
    const float* W1    = (const float*)d_in[3];
    const float* b1    = (const float*)d_in[4];
    const int*   idx0  = (const int*)d_in[5];   // [N0,32]
    const int*   idx1  = (const int*)d_in[6];   // [N1,32]
    // d_in[7] = node_ids1 — dead in the reference (v1 unused)
    const int*   nid2  = (const int*)d_in[8];   // [N2]

    const int N0 = in_sizes[5] / 32;            // 8192
    const int N1 = in_sizes[6] / 32;            // 100000

    const size_t need_f32 = (size_t)N1 * 64 * sizeof(float);   // 25.6 MB

    if (ws_size >= need_f32) {
        float* h1 = (float*)d_ws;
        k_hop1<float><<<2048, 256, 0, stream>>>(feats, W0, b0, idx1, nid2, h1, N1);
        k_hop0<float><<<2048, 256, 0, stream>>>(h1, W1, b1, idx0, (float*)d_out, N0);
    } else {
        bf16* h1 = (bf16*)d_ws;                 // 12.8 MB fallback
        k_hop1<bf16><<<2048, 256, 0, stream>>>(feats, W0, b0, idx1, nid2, h1, N1);
        k_hop0<bf16><<<2048, 256, 0, stream>>>(h1, W1, b1, idx0, (float*)d_out, N0);
    }
}

// Round 4
// 270.879 us; speedup vs baseline: 1.1689x; 1.1689x over previous
//
#include <hip/hip_runtime.h>
#include <hip/hip_bf16.h>

typedef __hip_bfloat16 bf16;

// Broadcast lane l's float value to all lanes (l uniform, full exec).
static __device__ __forceinline__ float lane_bcast_f(float v, int l) {
    return __uint_as_float(__builtin_amdgcn_readlane(__float_as_uint(v), l));
}

static __device__ __forceinline__ unsigned short f2bf_bits(float x) {
    bf16 h = __float2bfloat16(x);
    return *(unsigned short*)&h;
}

// Load chunk c4 (4 elements) of row `row` from a 64-wide table.
// Both fp32 (16 x float4 per row) and bf16 (16 x ushort4 per row) use chunk
// stride 16, so the addressing is identical.
static __device__ __forceinline__ float4 tload4(const float* p, size_t row, int c4) {
    return ((const float4*)p)[row * 16 + c4];
}
static __device__ __forceinline__ float4 tload4(const unsigned short* p, size_t row, int c4) {
    const ushort4 s = ((const ushort4*)p)[row * 16 + c4];
    float4 r;
    r.x = __uint_as_float((unsigned)s.x << 16);
    r.y = __uint_as_float((unsigned)s.y << 16);
    r.z = __uint_as_float((unsigned)s.z << 16);
    r.w = __uint_as_float((unsigned)s.w << 16);
    return r;
}

// Prologue: feats2[t][:] = bf16(feats[nid2[t]][:]) for t in [0,N2).
// Wave layout: lane=(sub<<4)|c4; quarter-wave `sub` handles one row; lane
// loads float4 cols 4*c4..4*c4+3 and stores ushort4. Two groups (8 rows)
// per iteration for ILP.
__global__ __launch_bounds__(256) void k_cast(
    const float* __restrict__ feats,   // [V,64] fp32
    const int*   __restrict__ nid2,    // [N2]
    unsigned short* __restrict__ feats2, // [N2,64] bf16 bits
    int N2)
{
    const int lane = threadIdx.x & 63;
    const int sub  = lane >> 4;
    const int c4   = lane & 15;
    const int gwave = blockIdx.x * (blockDim.x >> 6) + (threadIdx.x >> 6);
    const int nwave = gridDim.x * (blockDim.x >> 6);

    for (int base = 8 * gwave; base < N2; base += 8 * nwave) {
        const int t0 = base + sub;
        const int t1 = base + 4 + sub;
        const bool v0 = (t0 < N2), v1 = (t1 < N2);
        const int n0 = v0 ? nid2[t0] : 0;
        const int n1 = v1 ? nid2[t1] : 0;
        const float4 a = tload4(feats, (size_t)n0, c4);
        const float4 b = tload4(feats, (size_t)n1, c4);
        ushort4 sa, sb;
        sa.x = f2bf_bits(a.x); sa.y = f2bf_bits(a.y);
        sa.z = f2bf_bits(a.z); sa.w = f2bf_bits(a.w);
        sb.x = f2bf_bits(b.x); sb.y = f2bf_bits(b.y);
        sb.z = f2bf_bits(b.z); sb.w = f2bf_bits(b.w);
        if (v0) ((ushort4*)feats2)[(size_t)t0 * 16 + c4] = sa;
        if (v1) ((ushort4*)feats2)[(size_t)t1 * 16 + c4] = sb;
    }
}

// Hop-1: agg = mean_k table[idx or nid2[idx]], h1 = relu(agg@W0+b0) -> bf16.
// IND: resolve idx through nid2 (fallback path, fp32 table).
template <bool IND, typename TT>
__global__ __launch_bounds__(256) void k_hop1(
    const TT*    __restrict__ table,  // [*,64] feats2 (bf16) or feats (fp32)
    const float* __restrict__ W0,     // [64,64]
    const float* __restrict__ b0,     // [64]
    const int*   __restrict__ idx1,   // [N1,32]
    const int*   __restrict__ nid2,   // [N2] (used iff IND)
    unsigned short* __restrict__ h1,  // [N1,64] bf16 out
    int N1)
{
    const int lane = threadIdx.x & 63;
    const int sub  = lane >> 4;       // k-subset {sub, 4+sub, ..., 28+sub}
    const int c4   = lane & 15;       // cols 4*c4..4*c4+3
    const int gwave = blockIdx.x * (blockDim.x >> 6) + (threadIdx.x >> 6);
    const int nwave = gridDim.x * (blockDim.x >> 6);

    float w0c[64];
#pragma unroll
    for (int d = 0; d < 64; ++d) w0c[d] = W0[d * 64 + lane];
    const float bias = b0[lane];

    for (int base = 2 * gwave; base < N1; base += 2 * nwave) {
        const int r0 = base;
        const bool has_r1 = (base + 1 < N1);
        const int r1 = has_r1 ? base + 1 : base;

        int nk0[8], nk1[8];
#pragma unroll
        for (int i = 0; i < 8; ++i) {
            nk0[i] = idx1[r0 * 32 + 4 * i + sub];
            nk1[i] = idx1[r1 * 32 + 4 * i + sub];
        }
        if constexpr (IND) {
#pragma unroll
            for (int i = 0; i < 8; ++i) {
                nk0[i] = nid2[nk0[i]];
                nk1[i] = nid2[nk1[i]];
            }
        }

        float a0[4] = {0.f, 0.f, 0.f, 0.f};
        float a1[4] = {0.f, 0.f, 0.f, 0.f};
#pragma unroll
        for (int i = 0; i < 8; ++i) {
            const float4 v0 = tload4(table, (size_t)nk0[i], c4);
            const float4 v1 = tload4(table, (size_t)nk1[i], c4);
            a0[0] += v0.x; a0[1] += v0.y; a0[2] += v0.z; a0[3] += v0.w;
            a1[0] += v1.x; a1[1] += v1.y; a1[2] += v1.z; a1[3] += v1.w;
        }

#pragma unroll
        for (int c = 0; c < 4; ++c) {
            a0[c] += __shfl_xor(a0[c], 16, 64);
            a0[c] += __shfl_xor(a0[c], 32, 64);
            a1[c] += __shfl_xor(a1[c], 16, 64);
            a1[c] += __shfl_xor(a1[c], 32, 64);
            a0[c] *= 0.03125f;
            a1[c] *= 0.03125f;
        }

        float h0 = bias, h1v = bias;
#pragma unroll
        for (int d = 0; d < 64; ++d) {
            h0  = fmaf(lane_bcast_f(a0[d & 3], d >> 2), w0c[d], h0);
            h1v = fmaf(lane_bcast_f(a1[d & 3], d >> 2), w0c[d], h1v);
        }
        h0  = fmaxf(h0, 0.f);
        h1v = fmaxf(h1v, 0.f);

        h1[(size_t)r0 * 64 + lane] = f2bf_bits(h0);
        if (has_r1) h1[(size_t)r1 * 64 + lane] = f2bf_bits(h1v);
    }
}

// Seed layer: gather-mean over bf16 h1 rows, W1+b1+relu, fp32 out.
__global__ __launch_bounds__(256) void k_hop0(
    const unsigned short* __restrict__ h1,  // [N1,64] bf16
    const float* __restrict__ W1,     // [64,64]
    const float* __restrict__ b1,     // [64]
    const int*   __restrict__ idx0,   // [N0,32]
    float*       __restrict__ out,    // [N0,64] fp32
    int N0)
{
    const int lane = threadIdx.x & 63;
    const int sub  = lane >> 4;
    const int c4   = lane & 15;
    const int gwave = blockIdx.x * (blockDim.x >> 6) + (threadIdx.x >> 6);
    const int nwave = gridDim.x * (blockDim.x >> 6);

    float w1c[64];
#pragma unroll
    for (int d = 0; d < 64; ++d) w1c[d] = W1[d * 64 + lane];
    const float bias = b1[lane];

    for (int row = gwave; row < N0; row += nwave) {
        int jk[8];
#pragma unroll
        for (int i = 0; i < 8; ++i) jk[i] = idx0[row * 32 + 4 * i + sub];

        float a[4] = {0.f, 0.f, 0.f, 0.f};
#pragma unroll
        for (int i = 0; i < 8; ++i) {
            const float4 v = tload4(h1, (size_t)jk[i], c4);
            a[0] += v.x; a[1] += v.y; a[2] += v.z; a[3] += v.w;
        }
#pragma unroll
        for (int c = 0; c < 4; ++c) {
            a[c] += __shfl_xor(a[c], 16, 64);
            a[c] += __shfl_xor(a[c], 32, 64);
            a[c] *= 0.03125f;
        }

        float o = bias;
#pragma unroll
        for (int d = 0; d < 64; ++d)
            o = fmaf(lane_bcast_f(a[d & 3], d >> 2), w1c[d], o);
        out[(size_t)row * 64 + lane] = fmaxf(o, 0.f);
    }
}

extern "C" void kernel_launch(void* const* d_in, const int* in_sizes, int n_in,
                              void* d_out, int out_size, void* d_ws, size_t ws_size,
                              hipStream_t stream) {
    const float* feats = (const float*)d_in[0];
    const float* W0    = (const float*)d_in[1];
    const float* b0    = (const float*)d_in[2];
    const float* W1    = (const float*)d_in[3];
    const float* b1    = (const float*)d_in[4];
    const int*   idx0  = (const int*)d_in[5];   // [N0,32]
    const int*   idx1  = (const int*)d_in[6];   // [N1,32]
    // d_in[7] = node_ids1 — dead in the reference (v1 unused)
    const int*   nid2  = (const int*)d_in[8];   // [N2]

    const int N0 = in_sizes[5] / 32;            // 8192
    const int N1 = in_sizes[6] / 32;            // 100000
    const int N2 = in_sizes[8];                 // 300000

    const size_t bytes_feats2 = (size_t)N2 * 64 * 2;   // 38.4 MB
    const size_t bytes_h1     = (size_t)N1 * 64 * 2;   // 12.8 MB

    if (ws_size >= bytes_feats2 + bytes_h1) {
        // Fast path: bf16 gather table (half the bytes, no indirection).
        unsigned short* feats2 = (unsigned short*)d_ws;
        unsigned short* h1     = (unsigned short*)((char*)d_ws + bytes_feats2);
        k_cast<<<2048, 256, 0, stream>>>(feats, nid2, feats2, N2);
        k_hop1<false, unsigned short><<<2048, 256, 0, stream>>>(
            feats2, W0, b0, idx1, nullptr, h1, N1);
        k_hop0<<<2048, 256, 0, stream>>>(h1, W1, b1, idx0, (float*)d_out, N0);
    } else {
        // Fallback: gather fp32 feats through nid2; h1 still bf16 (12.8 MB).
        unsigned short* h1 = (unsigned short*)d_ws;
        k_hop1<true, float><<<2048, 256, 0, stream>>>(
            feats, W0, b0, idx1, nid2, h1, N1);
        k_hop0<<<2048, 256, 0, stream>>>(h1, W1, b1, idx0, (float*)d_out, N0);
    }
}

// Round 5
// 269.021 us; speedup vs baseline: 1.1769x; 1.0069x over previous
//
#include <hip/hip_runtime.h>
#include <hip/hip_bf16.h>

typedef __hip_bfloat16 bf16;

// Broadcast lane l's float value to all lanes (l uniform, full exec).
static __device__ __forceinline__ float lane_bcast_f(float v, int l) {
    return __uint_as_float(__builtin_amdgcn_readlane(__float_as_uint(v), l));
}

static __device__ __forceinline__ unsigned short f2bf_bits(float x) {
    bf16 h = __float2bfloat16(x);
    return *(unsigned short*)&h;
}

// Load chunk c4 (4 elements) of row `row` from a 64-wide table (chunk stride 16).
static __device__ __forceinline__ float4 tload4(const float* p, size_t row, int c4) {
    return ((const float4*)p)[row * 16 + c4];
}
static __device__ __forceinline__ float4 tload4(const unsigned short* p, size_t row, int c4) {
    const ushort4 s = ((const ushort4*)p)[row * 16 + c4];
    float4 r;
    r.x = __uint_as_float((unsigned)s.x << 16);
    r.y = __uint_as_float((unsigned)s.y << 16);
    r.z = __uint_as_float((unsigned)s.z << 16);
    r.w = __uint_as_float((unsigned)s.w << 16);
    return r;
}

// Prologue: feats2[t][:] = bf16(feats[nid2[t]][:]) for t in [0,N2).
// lane=(sub<<4)|c4; quarter-wave `sub` handles one row; lane moves 4 cols.
__global__ __launch_bounds__(256) void k_cast(
    const float* __restrict__ feats,     // [V,64] fp32
    const int*   __restrict__ nid2,      // [N2]
    unsigned short* __restrict__ feats2, // [N2,64] bf16 bits
    int N2)
{
    const int lane = threadIdx.x & 63;
    const int sub  = lane >> 4;
    const int c4   = lane & 15;
    const int gwave = blockIdx.x * (blockDim.x >> 6) + (threadIdx.x >> 6);
    const int nwave = gridDim.x * (blockDim.x >> 6);

    for (int base = 8 * gwave; base < N2; base += 8 * nwave) {
        const int t0 = base + sub;
        const int t1 = base + 4 + sub;
        const bool v0 = (t0 < N2), v1 = (t1 < N2);
        const int n0 = v0 ? nid2[t0] : 0;
        const int n1 = v1 ? nid2[t1] : 0;
        const float4 a = tload4(feats, (size_t)n0, c4);
        const float4 b = tload4(feats, (size_t)n1, c4);
        ushort4 sa, sb;
        sa.x = f2bf_bits(a.x); sa.y = f2bf_bits(a.y);
        sa.z = f2bf_bits(a.z); sa.w = f2bf_bits(a.w);
        sb.x = f2bf_bits(b.x); sb.y = f2bf_bits(b.y);
        sb.z = f2bf_bits(b.z); sb.w = f2bf_bits(b.w);
        if (v0) ((ushort4*)feats2)[(size_t)t0 * 16 + c4] = sa;
        if (v1) ((ushort4*)feats2)[(size_t)t1 * 16 + c4] = sb;
    }
}

// Hop-1: agg = mean_k table[idx (or nid2[idx])], h1 = relu(agg@W0+b0) -> bf16.
// lane=(sub<<4)|c4; quarter-wave sub covers CONTIGUOUS k in [8sub,8sub+8)
// so its 8 indices load as two int4. Two rows per iter for MLP.
template <bool IND, typename TT>
__global__ __launch_bounds__(256) void k_hop1(
    const TT*    __restrict__ table,  // feats2 (bf16) or feats (fp32)
    const float* __restrict__ W0,     // [64,64]
    const float* __restrict__ b0,     // [64]
    const int*   __restrict__ idx1,   // [N1,32]
    const int*   __restrict__ nid2,   // [N2] (used iff IND)
    unsigned short* __restrict__ h1,  // [N1,64] bf16 out
    int N1)
{
    const int lane = threadIdx.x & 63;
    const int sub  = lane >> 4;
    const int c4   = lane & 15;
    const int gwave = blockIdx.x * (blockDim.x >> 6) + (threadIdx.x >> 6);
    const int nwave = gridDim.x * (blockDim.x >> 6);

    float w0c[64];
#pragma unroll
    for (int d = 0; d < 64; ++d) w0c[d] = W0[d * 64 + lane];
    const float bias = b0[lane];

    const int4* iv = (const int4*)idx1;   // [N1, 8] int4

    for (int base = 2 * gwave; base < N1; base += 2 * nwave) {
        const int r0 = base;
        const bool has_r1 = (base + 1 < N1);
        const int r1 = has_r1 ? base + 1 : base;

        // 8 neighbor indices per quarter-wave as two int4 loads per row.
        const int4 qa0 = iv[(size_t)r0 * 8 + 2 * sub];
        const int4 qb0 = iv[(size_t)r0 * 8 + 2 * sub + 1];
        const int4 qa1 = iv[(size_t)r1 * 8 + 2 * sub];
        const int4 qb1 = iv[(size_t)r1 * 8 + 2 * sub + 1];
        int nk0[8] = {qa0.x, qa0.y, qa0.z, qa0.w, qb0.x, qb0.y, qb0.z, qb0.w};
        int nk1[8] = {qa1.x, qa1.y, qa1.z, qa1.w, qb1.x, qb1.y, qb1.z, qb1.w};
        if constexpr (IND) {
#pragma unroll
            for (int i = 0; i < 8; ++i) {
                nk0[i] = nid2[nk0[i]];
                nk1[i] = nid2[nk1[i]];
            }
        }

        // 16 independent row gathers in flight.
        float a0[4] = {0.f, 0.f, 0.f, 0.f};
        float a1[4] = {0.f, 0.f, 0.f, 0.f};
#pragma unroll
        for (int i = 0; i < 8; ++i) {
            const float4 v0 = tload4(table, (size_t)nk0[i], c4);
            const float4 v1 = tload4(table, (size_t)nk1[i], c4);
            a0[0] += v0.x; a0[1] += v0.y; a0[2] += v0.z; a0[3] += v0.w;
            a1[0] += v1.x; a1[1] += v1.y; a1[2] += v1.z; a1[3] += v1.w;
        }

        // Combine quarter-wave partials (lanes c4, c4+16, c4+32, c4+48).
#pragma unroll
        for (int c = 0; c < 4; ++c) {
            a0[c] += __shfl_xor(a0[c], 16, 64);
            a0[c] += __shfl_xor(a0[c], 32, 64);
            a1[c] += __shfl_xor(a1[c], 16, 64);
            a1[c] += __shfl_xor(a1[c], 32, 64);
            a0[c] *= 0.03125f;
            a1[c] *= 0.03125f;
        }

        // Broadcast matmul: h[lane] = relu(b[lane] + sum_d agg[d]*W0[d][lane]).
        float h0 = bias, h1v = bias;
#pragma unroll
        for (int d = 0; d < 64; ++d) {
            h0  = fmaf(lane_bcast_f(a0[d & 3], d >> 2), w0c[d], h0);
            h1v = fmaf(lane_bcast_f(a1[d & 3], d >> 2), w0c[d], h1v);
        }
        h0  = fmaxf(h0, 0.f);
        h1v = fmaxf(h1v, 0.f);

        h1[(size_t)r0 * 64 + lane] = f2bf_bits(h0);
        if (has_r1) h1[(size_t)r1 * 64 + lane] = f2bf_bits(h1v);
    }
}

// Seed layer: gather-mean over bf16 h1 rows, W1+b1+relu, fp32 out. 2-row ILP.
__global__ __launch_bounds__(256) void k_hop0(
    const unsigned short* __restrict__ h1,  // [N1,64] bf16
    const float* __restrict__ W1,     // [64,64]
    const float* __restrict__ b1,     // [64]
    const int*   __restrict__ idx0,   // [N0,32]
    float*       __restrict__ out,    // [N0,64] fp32
    int N0)
{
    const int lane = threadIdx.x & 63;
    const int sub  = lane >> 4;
    const int c4   = lane & 15;
    const int gwave = blockIdx.x * (blockDim.x >> 6) + (threadIdx.x >> 6);
    const int nwave = gridDim.x * (blockDim.x >> 6);

    float w1c[64];
#pragma unroll
    for (int d = 0; d < 64; ++d) w1c[d] = W1[d * 64 + lane];
    const float bias = b1[lane];

    const int4* iv = (const int4*)idx0;   // [N0, 8] int4

    for (int base = 2 * gwave; base < N0; base += 2 * nwave) {
        const int r0 = base;
        const bool has_r1 = (base + 1 < N0);
        const int r1 = has_r1 ? base + 1 : base;

        const int4 qa0 = iv[(size_t)r0 * 8 + 2 * sub];
        const int4 qb0 = iv[(size_t)r0 * 8 + 2 * sub + 1];
        const int4 qa1 = iv[(size_t)r1 * 8 + 2 * sub];
        const int4 qb1 = iv[(size_t)r1 * 8 + 2 * sub + 1];
        const int jk0[8] = {qa0.x, qa0.y, qa0.z, qa0.w, qb0.x, qb0.y, qb0.z, qb0.w};
        const int jk1[8] = {qa1.x, qa1.y, qa1.z, qa1.w, qb1.x, qb1.y, qb1.z, qb1.w};

        float a0[4] = {0.f, 0.f, 0.f, 0.f};
        float a1[4] = {0.f, 0.f, 0.f, 0.f};
#pragma unroll
        for (int i = 0; i < 8; ++i) {
            const float4 v0 = tload4(h1, (size_t)jk0[i], c4);
            const float4 v1 = tload4(h1, (size_t)jk1[i], c4);
            a0[0] += v0.x; a0[1] += v0.y; a0[2] += v0.z; a0[3] += v0.w;
            a1[0] += v1.x; a1[1] += v1.y; a1[2] += v1.z; a1[3] += v1.w;
        }
#pragma unroll
        for (int c = 0; c < 4; ++c) {
            a0[c] += __shfl_xor(a0[c], 16, 64);
            a0[c] += __shfl_xor(a0[c], 32, 64);
            a1[c] += __shfl_xor(a1[c], 16, 64);
            a1[c] += __shfl_xor(a1[c], 32, 64);
            a0[c] *= 0.03125f;
            a1[c] *= 0.03125f;
        }

        float o0 = bias, o1 = bias;
#pragma unroll
        for (int d = 0; d < 64; ++d) {
            o0 = fmaf(lane_bcast_f(a0[d & 3], d >> 2), w1c[d], o0);
            o1 = fmaf(lane_bcast_f(a1[d & 3], d >> 2), w1c[d], o1);
        }
        out[(size_t)r0 * 64 + lane] = fmaxf(o0, 0.f);
        if (has_r1) out[(size_t)r1 * 64 + lane] = fmaxf(o1, 0.f);
    }
}

extern "C" void kernel_launch(void* const* d_in, const int* in_sizes, int n_in,
                              void* d_out, int out_size, void* d_ws, size_t ws_size,
                              hipStream_t stream) {
    const float* feats = (const float*)d_in[0];
    const float* W0    = (const float*)d_in[1];
    const float* b0    = (const float*)d_in[2];
    const float* W1    = (const float*)d_in[3];
    const float* b1    = (const float*)d_in[4];
    const int*   idx0  = (const int*)d_in[5];   // [N0,32]
    const int*   idx1  = (const int*)d_in[6];   // [N1,32]
    // d_in[7] = node_ids1 — dead in the reference (v1 unused)
    const int*   nid2  = (const int*)d_in[8];   // [N2]

    const int N0 = in_sizes[5] / 32;            // 8192
    const int N1 = in_sizes[6] / 32;            // 100000
    const int N2 = in_sizes[8];                 // 300000

    const size_t bytes_feats2 = (size_t)N2 * 64 * 2;   // 38.4 MB
    const size_t bytes_h1     = (size_t)N1 * 64 * 2;   // 12.8 MB

    if (ws_size >= bytes_feats2 + bytes_h1) {
        unsigned short* feats2 = (unsigned short*)d_ws;
        unsigned short* h1     = (unsigned short*)((char*)d_ws + bytes_feats2);
        k_cast<<<2048, 256, 0, stream>>>(feats, nid2, feats2, N2);
        k_hop1<false, unsigned short><<<2048, 256, 0, stream>>>(
            feats2, W0, b0, idx1, nullptr, h1, N1);
        k_hop0<<<1024, 256, 0, stream>>>(h1, W1, b1, idx0, (float*)d_out, N0);
    } else {
        unsigned short* h1 = (unsigned short*)d_ws;
        k_hop1<true, float><<<2048, 256, 0, stream>>>(
            feats, W0, b0, idx1, nid2, h1, N1);
        k_hop0<<<1024, 256, 0, stream>>>(h1, W1, b1, idx0, (float*)d_out, N0);
    }
}